// Round 6
// baseline (669.558 us; speedup 1.0000x reference)
//
#include <hip/hip_runtime.h>

// Quantized vector-matrix multiply: out[n] = sum_k (x[k]-Xzp)*Xs * (y[k,n]-Yzp)*Ys
// Exact-integer reformulation:
//   out[n] = Xs*Ys * ( sum_k xs[k]*y[k,n] - Yzp*sum_k xs[k] ),  xs = x - X_ZP
// Max |acc| ~ 8192*152*127 ~ 1.6e8 -> fits int32 exactly.
//
// R5->R6: LINEAR-STREAM decomposition. Prior variants had each block read 4 KiB
// fragments at 64 KiB stride (measured ~3.7 TB/s even after phase-stagger).
// Now parallelize over K only: block kc owns rows [kc*16, kc*16+16) = 1 MiB of
// CONTIGUOUS y (the copy-kernel access shape, ~6.3 TB/s), keeping partials for
// all 16384 columns in registers (16 ivec4 accumulators/thread; thread t owns
// int4-columns {t, t+256, ..., t+3840}). Partials -> d_ws, two-stage reduce.

constexpr int K = 8192;
constexpr int N = 16384;
constexpr float X_SCALE = 0.0215f;
constexpr int   X_ZP    = -25;
constexpr float Y_SCALE = 0.0176f;
constexpr int   Y_ZP    = 18;

constexpr int BLOCK = 256;
constexpr int N4 = N / 4;                      // 4096 int4 per row
constexpr int SPLIT_K = 512;                   // one block per 16-row chunk
constexpr int KCHUNK = K / SPLIT_K;            // 16
constexpr int SEG = N4 / BLOCK;                // 16 int4 segments per thread

// reduce stage 1: 64 chunks -> 1, stage 2: 8 -> 1
constexpr int R1 = 64;
constexpr int R2 = SPLIT_K / R1;               // 8

typedef int ivec4 __attribute__((ext_vector_type(4)));

__global__ __launch_bounds__(BLOCK, 2) void qgemv_partial(const int* __restrict__ x,
                                                          const ivec4* __restrict__ y,
                                                          ivec4* __restrict__ ws) {
    __shared__ int xs[KCHUNK];

    const int kc = blockIdx.x;
    const int k0 = kc * KCHUNK;

    if (threadIdx.x < KCHUNK)
        xs[threadIdx.x] = x[k0 + threadIdx.x] - X_ZP;
    __syncthreads();

    const ivec4* yv = y + (size_t)k0 * N4;

    ivec4 acc[SEG];
#pragma unroll
    for (int i = 0; i < SEG; ++i) acc[i] = (ivec4)0;
    int sx = 0;

    // Block streams 16 rows x 64 KiB = 1 MiB fully contiguous.
    for (int k = 0; k < KCHUNK; ++k) {
        const int a = xs[k];
        sx += a;
        const ivec4* row = yv + (size_t)k * N4;
#pragma unroll
        for (int i = 0; i < SEG; ++i) {
            ivec4 v = __builtin_nontemporal_load(&row[threadIdx.x + BLOCK * i]);
            acc[i] += v * a;
        }
    }

    // Fold this chunk's zero-point correction -> reduce is a pure sum.
    const int corr = Y_ZP * sx;
    ivec4* wrow = ws + (size_t)kc * N4;
#pragma unroll
    for (int i = 0; i < SEG; ++i)
        wrow[threadIdx.x + BLOCK * i] = acc[i] - corr;
}

// Stage 1: sum R1=64 chunk-partials per column group. Grid (N4/BLOCK, R2).
__global__ __launch_bounds__(BLOCK) void qgemv_reduce1(const ivec4* __restrict__ ws,
                                                       ivec4* __restrict__ ws2) {
    const int col4 = blockIdx.x * BLOCK + threadIdx.x;
    const int kb = blockIdx.y;
    ivec4 s = (ivec4)0;
#pragma unroll 8
    for (int j = 0; j < R1; ++j)
        s += ws[(size_t)(kb * R1 + j) * N4 + col4];
    ws2[(size_t)kb * N4 + col4] = s;
}

// Stage 2: sum R2=8 partials, scale, store fp32. Grid (N4/BLOCK).
__global__ __launch_bounds__(BLOCK) void qgemv_reduce2(const ivec4* __restrict__ ws2,
                                                       float* __restrict__ out) {
    const int col4 = blockIdx.x * BLOCK + threadIdx.x;
    ivec4 s = (ivec4)0;
#pragma unroll
    for (int j = 0; j < R2; ++j)
        s += ws2[(size_t)j * N4 + col4];
    const float sc = X_SCALE * Y_SCALE;
    float4 o;
    o.x = sc * (float)s.x;
    o.y = sc * (float)s.y;
    o.z = sc * (float)s.z;
    o.w = sc * (float)s.w;
    ((float4*)out)[col4] = o;
}

extern "C" void kernel_launch(void* const* d_in, const int* in_sizes, int n_in,
                              void* d_out, int out_size, void* d_ws, size_t ws_size,
                              hipStream_t stream) {
    const int* x = (const int*)d_in[0];
    const ivec4* y = (const ivec4*)d_in[1];
    float* out = (float*)d_out;

    ivec4* ws  = (ivec4*)d_ws;                          // 512 x 4096 x 16 B = 32 MiB
    ivec4* ws2 = ws + (size_t)SPLIT_K * N4;             // + 8 x 4096 x 16 B = 512 KiB

    qgemv_partial<<<SPLIT_K, BLOCK, 0, stream>>>(x, y, ws);
    qgemv_reduce1<<<dim3(N4 / BLOCK, R2), BLOCK, 0, stream>>>(ws, ws2);
    qgemv_reduce2<<<N4 / BLOCK, BLOCK, 0, stream>>>(ws2, out);
}